// Round 1
// baseline (973.847 us; speedup 1.0000x reference)
//
#include <hip/hip_runtime.h>
#include <math.h>

#define MAX_VEL 0.9f
#define REL_EPS 1e-6f

// ---------------- dense linear: Y[N,64] = X[N,64] @ W[64,64] + b ----------------
__global__ void linear64(const float* __restrict__ X, const float* __restrict__ W,
                         const float* __restrict__ b, float* __restrict__ Y, int N)
{
    __shared__ float sW[64 * 64];
    __shared__ float sB[64];
    for (int i = threadIdx.x; i < 64 * 64; i += blockDim.x) sW[i] = W[i];
    if (threadIdx.x < 64) sB[threadIdx.x] = b[threadIdx.x];
    __syncthreads();
    int node = blockIdx.x * 4 + (threadIdx.x >> 6);
    int c = threadIdx.x & 63;
    if (node >= N) return;
    const float* xr = X + (size_t)node * 64;
    float acc = sB[c];
#pragma unroll
    for (int k = 0; k < 64; ++k) acc = fmaf(xr[k], sW[k * 64 + c], acc);
    Y[(size_t)node * 64 + c] = acc;
}

// ---------------- dense linear: Y[N,32] = X[N,64] @ W[64,32] + b ----------------
__global__ void linear32(const float* __restrict__ X, const float* __restrict__ W,
                         const float* __restrict__ b, float* __restrict__ Y, int N)
{
    __shared__ float sW[64 * 32];
    __shared__ float sB[32];
    for (int i = threadIdx.x; i < 64 * 32; i += blockDim.x) sW[i] = W[i];
    if (threadIdx.x < 32) sB[threadIdx.x] = b[threadIdx.x];
    __syncthreads();
    int node = blockIdx.x * 8 + (threadIdx.x >> 5);
    int c = threadIdx.x & 31;
    if (node >= N) return;
    const float* xr = X + (size_t)node * 64;
    float acc = sB[c];
#pragma unroll
    for (int k = 0; k < 64; ++k) acc = fmaf(xr[k], sW[k * 32 + c], acc);
    Y[(size_t)node * 32 + c] = acc;
}

// ---- layer-1 edge kernel: one wave per edge. Weight from x, message from h1 (64ch). ----
__global__ void edge_scatter1(const float* __restrict__ x, const float* __restrict__ h1,
                              const int* __restrict__ src, const int* __restrict__ dst,
                              float* __restrict__ agg, float* __restrict__ deg, int E)
{
    int gid = blockIdx.x * blockDim.x + threadIdx.x;
    int edge = gid >> 6;
    int lane = threadIdx.x & 63;
    if (edge >= E) return;
    int s = src[edge];
    int d = dst[edge];
    float xs = x[(size_t)s * 64 + lane];
    float xd = x[(size_t)d * 64 + lane];
    float df = xs - xd;
    float sq = df * df;
#pragma unroll
    for (int off = 32; off; off >>= 1) sq += __shfl_xor(sq, off);
    float v = tanhf(sqrtf(sq)) * MAX_VEL;
    float w = sqrtf(1.0f - v * v + REL_EPS);   // == 1/gamma
    float msg = h1[(size_t)s * 64 + lane] * w;
    atomicAdd(&agg[(size_t)d * 64 + lane], msg);
    if (lane == 0) atomicAdd(&deg[d], 1.0f);
}

// ---- layer-2 edge kernel: weight from h (64ch), message from h2 (32ch) into d_out. ----
__global__ void edge_scatter2(const float* __restrict__ h, const float* __restrict__ h2,
                              const int* __restrict__ src, const int* __restrict__ dst,
                              float* __restrict__ out, int E)
{
    int gid = blockIdx.x * blockDim.x + threadIdx.x;
    int edge = gid >> 6;
    int lane = threadIdx.x & 63;
    if (edge >= E) return;
    int s = src[edge];
    int d = dst[edge];
    float hs = h[(size_t)s * 64 + lane];
    float hd = h[(size_t)d * 64 + lane];
    float df = hs - hd;
    float sq = df * df;
#pragma unroll
    for (int off = 32; off; off >>= 1) sq += __shfl_xor(sq, off);
    float v = tanhf(sqrtf(sq)) * MAX_VEL;
    float w = sqrtf(1.0f - v * v + REL_EPS);
    if (lane < 32) {
        float msg = h2[(size_t)s * 32 + lane] * w;
        atomicAdd(&out[(size_t)d * 32 + lane], msg);
    }
}

// ---- normalize by degree (+ optional relu), elementwise over N*C ----
__global__ void norm_relu64(const float* __restrict__ agg, const float* __restrict__ deg,
                            float* __restrict__ h, int N)
{
    int i = blockIdx.x * blockDim.x + threadIdx.x;
    if (i >= N * 64) return;
    int node = i >> 6;
    float dv = deg[node];
    dv = dv > 1.0f ? dv : 1.0f;
    float val = agg[i] / dv;
    h[i] = val > 0.0f ? val : 0.0f;
}

__global__ void norm_out32(const float* __restrict__ deg, float* __restrict__ out, int N)
{
    int i = blockIdx.x * blockDim.x + threadIdx.x;
    if (i >= N * 32) return;
    int node = i >> 5;
    float dv = deg[node];
    dv = dv > 1.0f ? dv : 1.0f;
    out[i] = out[i] / dv;
}

extern "C" void kernel_launch(void* const* d_in, const int* in_sizes, int n_in,
                              void* d_out, int out_size, void* d_ws, size_t ws_size,
                              hipStream_t stream)
{
    const float* x  = (const float*)d_in[0];
    const int*   ei = (const int*)d_in[1];
    const float* W1 = (const float*)d_in[2];
    const float* b1 = (const float*)d_in[3];
    const float* W2 = (const float*)d_in[4];
    const float* b2 = (const float*)d_in[5];
    float* out = (float*)d_out;

    const int N = in_sizes[0] / 64;
    const int E = in_sizes[1] / 2;
    const int* src = ei;
    const int* dst = ei + E;

    float* ws   = (float*)d_ws;
    float* h1   = ws;                          // N*64: linear1 out; reused as relu'd hidden
    float* agg  = h1  + (size_t)N * 64;        // N*64: layer-1 aggregation
    float* h2   = agg + (size_t)N * 64;        // N*32: linear2 out
    float* deg  = h2  + (size_t)N * 32;        // N: in-degree

    hipMemsetAsync(agg, 0, (size_t)N * 64 * sizeof(float), stream);
    hipMemsetAsync(deg, 0, (size_t)N * sizeof(float), stream);
    hipMemsetAsync(out, 0, (size_t)N * 32 * sizeof(float), stream);

    linear64<<<(N + 3) / 4, 256, 0, stream>>>(x, W1, b1, h1, N);

    int eblocks = (int)(((size_t)E * 64 + 255) / 256);
    edge_scatter1<<<eblocks, 256, 0, stream>>>(x, h1, src, dst, agg, deg, E);

    norm_relu64<<<(N * 64 + 255) / 256, 256, 0, stream>>>(agg, deg, h1, N);

    linear32<<<(N + 7) / 8, 256, 0, stream>>>(h1, W2, b2, h2, N);

    edge_scatter2<<<eblocks, 256, 0, stream>>>(h1, h2, src, dst, out, E);

    norm_out32<<<(N * 32 + 255) / 256, 256, 0, stream>>>(deg, out, N);
}